// Round 1
// baseline (112.025 us; speedup 1.0000x reference)
//
#include <hip/hip_runtime.h>
#include <math.h>

// Problem constants (from reference)
#define BATCH     65536
#define NNBR      8
#define DIM       16
// L2_WEIGHT * 0.5
#define HALF_L2W  5.0e-5f

// d_ws layout: ws[0] = l2 sum-of-squares accumulator, ws[1] = bce sum accumulator

// ---------------------------------------------------------------------------
// Kernel 1: sum of squares over the three embedding tables (streaming, float4)
// ---------------------------------------------------------------------------
__global__ void l2_kernel(const float4* __restrict__ ue,
                          const float4* __restrict__ ee,
                          const float4* __restrict__ re,
                          int n_u4, int n_e4, int n_r4,
                          float* __restrict__ ws) {
    float acc = 0.0f;
    int tid    = blockIdx.x * blockDim.x + threadIdx.x;
    int stride = gridDim.x * blockDim.x;

    for (int i = tid; i < n_e4; i += stride) {
        float4 v = ee[i];
        acc += v.x * v.x + v.y * v.y + v.z * v.z + v.w * v.w;
    }
    for (int i = tid; i < n_u4; i += stride) {
        float4 v = ue[i];
        acc += v.x * v.x + v.y * v.y + v.z * v.z + v.w * v.w;
    }
    for (int i = tid; i < n_r4; i += stride) {
        float4 v = re[i];
        acc += v.x * v.x + v.y * v.y + v.z * v.z + v.w * v.w;
    }

    // wave (64-lane) reduction
    #pragma unroll
    for (int o = 32; o > 0; o >>= 1) acc += __shfl_down(acc, o);

    __shared__ float smem[4];           // 256 threads = 4 waves
    int wid = threadIdx.x >> 6;
    if ((threadIdx.x & 63) == 0) smem[wid] = acc;
    __syncthreads();
    if (threadIdx.x == 0) {
        float t = smem[0] + smem[1] + smem[2] + smem[3];
        atomicAdd(&ws[0], t);
    }
}

// ---------------------------------------------------------------------------
// Kernel 2: per-row KGCN forward + BCE. 16 lanes per row (lane = dim).
// Block = 256 threads = 16 rows. Grid = BATCH/16 = 4096 blocks.
// ---------------------------------------------------------------------------
__global__ void row_kernel(const float* __restrict__ ue,
                           const float* __restrict__ ee,
                           const float* __restrict__ re,
                           const float* __restrict__ W,     // [D][D], applied as x @ W.T -> item_d = sum_j W[d][j] x_j
                           const float* __restrict__ bias,  // [D]
                           const float* __restrict__ labels,
                           const int*   __restrict__ uidx,
                           const int*   __restrict__ iidx,
                           const int*   __restrict__ adjE,  // [N_ENTITY][K]
                           const int*   __restrict__ adjR,
                           float* __restrict__ ws) {
    __shared__ float sW[DIM * DIM];
    __shared__ float sb[DIM];
    if (threadIdx.x < DIM * DIM) sW[threadIdx.x] = W[threadIdx.x];
    if (threadIdx.x < DIM)       sb[threadIdx.x] = bias[threadIdx.x];
    __syncthreads();

    const int lane = threadIdx.x & 15;          // dim index d
    const int grp  = threadIdx.x >> 4;          // row-in-block 0..15
    const int row  = blockIdx.x * 16 + grp;     // BATCH divisible by 16

    const int ui = uidx[row];
    const int it = iidx[row];

    const float u  = ue[ui * DIM + lane];
    const float sv = ee[it * DIM + lane];

    int ne[NNBR], nr[NNBR];
    #pragma unroll
    for (int k = 0; k < NNBR; ++k) {
        ne[k] = adjE[it * NNBR + k];
        nr[k] = adjR[it * NNBR + k];
    }

    float nv[NNBR];
    float sc[NNBR];
    #pragma unroll
    for (int k = 0; k < NNBR; ++k) {
        const float rv = re[nr[k] * DIM + lane];   // only 64 relations -> cache-hot
        nv[k] = ee[ne[k] * DIM + lane];            // random gather
        float s = u * rv;
        #pragma unroll
        for (int o = 8; o > 0; o >>= 1) s += __shfl_xor(s, o, 16);
        sc[k] = s * (1.0f / 16.0f);                // mean over D
    }

    // softmax over K (replicated on all 16 lanes)
    float m = sc[0];
    #pragma unroll
    for (int k = 1; k < NNBR; ++k) m = fmaxf(m, sc[k]);
    float den = 0.0f;
    float e[NNBR];
    #pragma unroll
    for (int k = 0; k < NNBR; ++k) { e[k] = __expf(sc[k] - m); den += e[k]; }
    const float inv = 1.0f / den;

    float agg = 0.0f;
    #pragma unroll
    for (int k = 0; k < NNBR; ++k) agg += e[k] * nv[k];
    agg *= inv;

    const float x = sv + agg;                      // lane d holds x_d

    // item_d = tanh(sum_j W[d][j] * x_j + b_d)
    float acc = sb[lane];
    #pragma unroll
    for (int j = 0; j < DIM; ++j) {
        const float xj = __shfl(x, j, 16);
        acc += sW[lane * DIM + j] * xj;
    }
    const float item = tanhf(acc);

    float lg = u * item;
    #pragma unroll
    for (int o = 8; o > 0; o >>= 1) lg += __shfl_xor(lg, o, 16);

    // BCE (stable): max(x,0) - x*y + log1p(exp(-|x|)); only lane 0 of each group
    float term = 0.0f;
    if (lane == 0) {
        const float y = labels[row];
        term = fmaxf(lg, 0.0f) - lg * y + log1pf(__expf(-fabsf(lg)));
    }

    // wave reduction (4 groups per 64-lane wave contribute)
    #pragma unroll
    for (int o = 32; o > 0; o >>= 1) term += __shfl_down(term, o);

    __shared__ float sred[4];
    int wid = threadIdx.x >> 6;
    if ((threadIdx.x & 63) == 0) sred[wid] = term;
    __syncthreads();
    if (threadIdx.x == 0) {
        float t = sred[0] + sred[1] + sred[2] + sred[3];
        atomicAdd(&ws[1], t);
    }
}

// ---------------------------------------------------------------------------
// Kernel 3: finalize
// ---------------------------------------------------------------------------
__global__ void finalize_kernel(const float* __restrict__ ws, float* __restrict__ out) {
    if (threadIdx.x == 0 && blockIdx.x == 0) {
        out[0] = ws[1] * (1.0f / (float)BATCH) + HALF_L2W * ws[0];
    }
}

extern "C" void kernel_launch(void* const* d_in, const int* in_sizes, int n_in,
                              void* d_out, int out_size, void* d_ws, size_t ws_size,
                              hipStream_t stream) {
    const float* user_emb     = (const float*)d_in[0];
    const float* entity_emb   = (const float*)d_in[1];
    const float* relation_emb = (const float*)d_in[2];
    const float* agg_W        = (const float*)d_in[3];
    const float* agg_b        = (const float*)d_in[4];
    const float* labels       = (const float*)d_in[5];
    const int*   user_indices = (const int*)d_in[6];
    const int*   item_indices = (const int*)d_in[7];
    const int*   adj_entity   = (const int*)d_in[8];
    const int*   adj_relation = (const int*)d_in[9];

    float* ws  = (float*)d_ws;
    float* out = (float*)d_out;

    const int n_u4 = in_sizes[0] / 4;
    const int n_e4 = in_sizes[1] / 4;
    const int n_r4 = in_sizes[2] / 4;

    hipMemsetAsync(d_ws, 0, 2 * sizeof(float), stream);

    l2_kernel<<<2048, 256, 0, stream>>>(
        (const float4*)user_emb, (const float4*)entity_emb, (const float4*)relation_emb,
        n_u4, n_e4, n_r4, ws);

    row_kernel<<<BATCH / 16, 256, 0, stream>>>(
        user_emb, entity_emb, relation_emb, agg_W, agg_b, labels,
        user_indices, item_indices, adj_entity, adj_relation, ws);

    finalize_kernel<<<1, 64, 0, stream>>>(ws, out);
}

// Round 2
// 46.164 us; speedup vs baseline: 2.4267x; 2.4267x over previous
//
#include <hip/hip_runtime.h>
#include <math.h>

// Problem constants (from reference)
#define BATCH     65536
#define NNBR      8
#define DIM       16
#define HALF_L2W  5.0e-5f   // 0.5 * L2_WEIGHT

#define FUSED_GRID   4096        // = BATCH/16
#define FUSED_BLOCK  256
// ws layout: ws[2*b] = l2 partial of block b, ws[2*b+1] = bce partial of block b

// ---------------------------------------------------------------------------
// Fused kernel: per-row KGCN forward + BCE (16 lanes/row) AND grid-stride
// sum-of-squares over the three embedding tables. Partials stored per block
// (plain stores -> no init/memset needed).
// ---------------------------------------------------------------------------
__global__ void __launch_bounds__(FUSED_BLOCK)
fused_kernel(const float* __restrict__ ue,
             const float* __restrict__ ee,
             const float* __restrict__ re,
             const float* __restrict__ W,     // [D][D]: item_d = sum_j W[d][j] x_j
             const float* __restrict__ bias,  // [D]
             const float* __restrict__ labels,
             const int*   __restrict__ uidx,
             const int*   __restrict__ iidx,
             const int*   __restrict__ adjE,  // [N_ENTITY][K]
             const int*   __restrict__ adjR,
             int n_u4, int n_e4, int n_r4,
             float* __restrict__ ws) {
    __shared__ float sW[DIM * DIM];
    __shared__ float sb[DIM];
    if (threadIdx.x < DIM * DIM) sW[threadIdx.x] = W[threadIdx.x];
    if (threadIdx.x < DIM)       sb[threadIdx.x] = bias[threadIdx.x];
    __syncthreads();

    // ---------------- row work: 16 lanes per row ----------------
    const int lane = threadIdx.x & 15;          // dim index d
    const int grp  = threadIdx.x >> 4;          // row-in-block 0..15
    const int row  = blockIdx.x * 16 + grp;

    const int ui = uidx[row];
    const int it = iidx[row];

    const float u  = ue[ui * DIM + lane];
    const float sv = ee[it * DIM + lane];

    int ne[NNBR], nr[NNBR];
    #pragma unroll
    for (int k = 0; k < NNBR; ++k) {
        ne[k] = adjE[it * NNBR + k];
        nr[k] = adjR[it * NNBR + k];
    }

    float nv[NNBR];
    float sc[NNBR];
    #pragma unroll
    for (int k = 0; k < NNBR; ++k) {
        const float rv = re[nr[k] * DIM + lane];   // 64 relations -> cache-hot
        nv[k] = ee[ne[k] * DIM + lane];            // random gather (L3-backed)
        float s = u * rv;
        #pragma unroll
        for (int o = 8; o > 0; o >>= 1) s += __shfl_xor(s, o, 16);
        sc[k] = s * (1.0f / 16.0f);                // mean over D
    }

    // softmax over K (replicated on all 16 lanes)
    float m = sc[0];
    #pragma unroll
    for (int k = 1; k < NNBR; ++k) m = fmaxf(m, sc[k]);
    float den = 0.0f;
    float e[NNBR];
    #pragma unroll
    for (int k = 0; k < NNBR; ++k) { e[k] = __expf(sc[k] - m); den += e[k]; }
    const float inv = 1.0f / den;

    float agg = 0.0f;
    #pragma unroll
    for (int k = 0; k < NNBR; ++k) agg += e[k] * nv[k];
    agg *= inv;

    const float x = sv + agg;                      // lane d holds x_d

    float acc = sb[lane];
    #pragma unroll
    for (int j = 0; j < DIM; ++j) {
        const float xj = __shfl(x, j, 16);
        acc += sW[lane * DIM + j] * xj;
    }
    const float item = tanhf(acc);

    float lg = u * item;
    #pragma unroll
    for (int o = 8; o > 0; o >>= 1) lg += __shfl_xor(lg, o, 16);

    float bce = 0.0f;
    if (lane == 0) {
        const float y = labels[row];
        bce = fmaxf(lg, 0.0f) - lg * y + log1pf(__expf(-fabsf(lg)));
    }

    // ---------------- L2 work: grid-stride streaming ----------------
    const float4* ue4 = (const float4*)ue;
    const float4* ee4 = (const float4*)ee;
    const float4* re4 = (const float4*)re;

    float l2 = 0.0f;
    {
        const int tid    = blockIdx.x * FUSED_BLOCK + threadIdx.x;
        const int stride = FUSED_GRID * FUSED_BLOCK;
        for (int i = tid; i < n_e4; i += stride) {
            float4 v = ee4[i];
            l2 += v.x * v.x + v.y * v.y + v.z * v.z + v.w * v.w;
        }
        for (int i = tid; i < n_u4; i += stride) {
            float4 v = ue4[i];
            l2 += v.x * v.x + v.y * v.y + v.z * v.z + v.w * v.w;
        }
        for (int i = tid; i < n_r4; i += stride) {
            float4 v = re4[i];
            l2 += v.x * v.x + v.y * v.y + v.z * v.z + v.w * v.w;
        }
    }

    // ---------------- block reduction of both partials ----------------
    #pragma unroll
    for (int o = 32; o > 0; o >>= 1) {
        bce += __shfl_down(bce, o);
        l2  += __shfl_down(l2, o);
    }

    __shared__ float sred[8];                   // 4 waves x {l2, bce}
    const int wid = threadIdx.x >> 6;
    if ((threadIdx.x & 63) == 0) { sred[wid] = l2; sred[4 + wid] = bce; }
    __syncthreads();
    if (threadIdx.x == 0) {
        ws[2 * blockIdx.x]     = sred[0] + sred[1] + sred[2] + sred[3];
        ws[2 * blockIdx.x + 1] = sred[4] + sred[5] + sred[6] + sred[7];
    }
}

// ---------------------------------------------------------------------------
// Finalize: reduce 4096 {l2, bce} partial pairs, emit scalar loss.
// ---------------------------------------------------------------------------
__global__ void __launch_bounds__(256)
finalize_kernel(const float* __restrict__ ws, float* __restrict__ out) {
    float l2 = 0.0f, bce = 0.0f;
    for (int i = threadIdx.x; i < FUSED_GRID; i += 256) {
        l2  += ws[2 * i];
        bce += ws[2 * i + 1];
    }
    #pragma unroll
    for (int o = 32; o > 0; o >>= 1) {
        l2  += __shfl_down(l2, o);
        bce += __shfl_down(bce, o);
    }
    __shared__ float sred[8];
    const int wid = threadIdx.x >> 6;
    if ((threadIdx.x & 63) == 0) { sred[wid] = l2; sred[4 + wid] = bce; }
    __syncthreads();
    if (threadIdx.x == 0) {
        const float l2t  = sred[0] + sred[1] + sred[2] + sred[3];
        const float bcet = sred[4] + sred[5] + sred[6] + sred[7];
        out[0] = bcet * (1.0f / (float)BATCH) + HALF_L2W * l2t;
    }
}

extern "C" void kernel_launch(void* const* d_in, const int* in_sizes, int n_in,
                              void* d_out, int out_size, void* d_ws, size_t ws_size,
                              hipStream_t stream) {
    const float* user_emb     = (const float*)d_in[0];
    const float* entity_emb   = (const float*)d_in[1];
    const float* relation_emb = (const float*)d_in[2];
    const float* agg_W        = (const float*)d_in[3];
    const float* agg_b        = (const float*)d_in[4];
    const float* labels       = (const float*)d_in[5];
    const int*   user_indices = (const int*)d_in[6];
    const int*   item_indices = (const int*)d_in[7];
    const int*   adj_entity   = (const int*)d_in[8];
    const int*   adj_relation = (const int*)d_in[9];

    float* ws  = (float*)d_ws;
    float* out = (float*)d_out;

    const int n_u4 = in_sizes[0] / 4;
    const int n_e4 = in_sizes[1] / 4;
    const int n_r4 = in_sizes[2] / 4;

    fused_kernel<<<FUSED_GRID, FUSED_BLOCK, 0, stream>>>(
        user_emb, entity_emb, relation_emb, agg_W, agg_b, labels,
        user_indices, item_indices, adj_entity, adj_relation,
        n_u4, n_e4, n_r4, ws);

    finalize_kernel<<<1, 256, 0, stream>>>(ws, out);
}